// Round 1
// baseline (6461.360 us; speedup 1.0000x reference)
//
#include <hip/hip_runtime.h>
#include <hip/hip_bf16.h>
#include <math.h>

// ---------------- problem constants ----------------
constexpr int N_NODES = 100000;
constexpr int N_EDGES = 800000;
constexpr int NB      = 64;
constexpr int IN_F    = 256;
constexpr int HC1C    = 128;
constexpr int HC2C    = 32;
constexpr int SA_D    = 350;
constexpr float NEG   = 0.2f;

// ---------------- workspace layout (floats) ----------------
constexpr size_t OFF_WCL    = 0;                                   // 256*128
constexpr size_t OFF_WCR    = OFF_WCL + (size_t)IN_F * HC1C;       // 256*128
constexpr size_t OFF_BCL    = OFF_WCR + (size_t)IN_F * HC1C;       // 128
constexpr size_t OFF_BCR    = OFF_BCL + HC1C;                      // 128
constexpr size_t OFF_XLR    = OFF_BCR + HC1C;                      // N*256 (xlr1; reused xlr2/xlr3)
constexpr size_t OFF_H      = OFF_XLR + (size_t)N_NODES * 256;     // N*128 (acc1/h1/acc2/h2/acc3/h3)
constexpr size_t OFF_EX     = OFF_H + (size_t)N_NODES * 128;       // E
constexpr size_t OFF_DEN    = OFF_EX + N_EDGES;                    // N
constexpr size_t OFF_POOLED = OFF_DEN + N_NODES;                   // 64*32
constexpr size_t OFF_CNT    = OFF_POOLED + NB * HC2C;              // 64
constexpr size_t OFF_SX     = OFF_CNT + NB;                        // 64*32
constexpr size_t OFF_INFO   = OFF_SX + NB * HC2C;                  // 64*254
constexpr size_t OFF_T1     = OFF_INFO + (size_t)NB * (IN_F - 2);  // 128*64
constexpr size_t OFF_T2     = OFF_T1 + (size_t)HC1C * NB;          // 64*64
constexpr size_t OFF_TT     = OFF_T2 + (size_t)NB * NB;            // 64*32
constexpr size_t WS_FLOATS  = OFF_TT + NB * HC2C;

// ---------------- kernels ----------------

// WcL = Wv @ Wl1, WcR = Wv @ Wr1   (256x350)@(350x128) -> (256x128)
__global__ void k_wcomb(const float* __restrict__ Wv, const float* __restrict__ Wl1,
                        const float* __restrict__ Wr1, float* __restrict__ WcL,
                        float* __restrict__ WcR) {
  int t = blockIdx.x * blockDim.x + threadIdx.x;
  if (t >= IN_F * HC1C) return;
  int i = t / HC1C, j = t - (t / HC1C) * HC1C;
  float al = 0.f, ar = 0.f;
  for (int k = 0; k < SA_D; ++k) {
    float wv = Wv[i * SA_D + k];
    al += wv * Wl1[k * HC1C + j];
    ar += wv * Wr1[k * HC1C + j];
  }
  WcL[t] = al;
  WcR[t] = ar;
}

// bcL = bv @ Wl1 + bl1, bcR = bv @ Wr1 + br1
__global__ void k_bcomb(const float* __restrict__ bv, const float* __restrict__ Wl1,
                        const float* __restrict__ bl1, const float* __restrict__ Wr1,
                        const float* __restrict__ br1, float* __restrict__ bcL,
                        float* __restrict__ bcR) {
  int j = threadIdx.x;
  if (j >= HC1C) return;
  float al = bl1[j], ar = br1[j];
  for (int k = 0; k < SA_D; ++k) {
    al += bv[k] * Wl1[k * HC1C + j];
    ar += bv[k] * Wr1[k * HC1C + j];
  }
  bcL[j] = al;
  bcR[j] = ar;
}

// out (N, 2C) = [ x@Wl + bl | x@Wr + br ].  blockDim = C, each block does TN rows.
template <int TN, int K, int C>
__global__ __launch_bounds__(C) void k_gemm_lr(const float* __restrict__ x,
                                               const float* __restrict__ Wl,
                                               const float* __restrict__ bl,
                                               const float* __restrict__ Wr,
                                               const float* __restrict__ br,
                                               float* __restrict__ out) {
  __shared__ __align__(16) float xs[K * TN];  // transposed tile: xs[k*TN + r]
  const int m = threadIdx.x;                  // column within C
  const size_t n0 = (size_t)blockIdx.x * TN;
  for (int i = m; i < TN * K; i += C) {
    int r = i / K;
    int k = i - r * K;
    xs[k * TN + r] = x[n0 * K + i];
  }
  __syncthreads();
  float accL[TN], accR[TN];
#pragma unroll
  for (int r = 0; r < TN; ++r) { accL[r] = 0.f; accR[r] = 0.f; }
#pragma unroll 4
  for (int k = 0; k < K; ++k) {
    float wl = Wl[(size_t)k * C + m];
    float wr = Wr[(size_t)k * C + m];
    const float4* xv = (const float4*)(xs + k * TN);
    float4 a = xv[0];
    float4 b4 = xv[1];
    float xr8[8] = {a.x, a.y, a.z, a.w, b4.x, b4.y, b4.z, b4.w};
#pragma unroll
    for (int r = 0; r < TN; ++r) {
      accL[r] += xr8[r] * wl;
      accR[r] += xr8[r] * wr;
    }
  }
#pragma unroll
  for (int r = 0; r < TN; ++r) {
    out[(n0 + r) * (2 * C) + m]     = accL[r] + bl[m];
    out[(n0 + r) * (2 * C) + C + m] = accR[r] + br[m];
  }
}

// Edge pass A: ex[e] = exp(att . lrelu(xl[src]+xr[dst])); den[dst] += ex
template <int C>
__global__ void k_edge_score(const float* __restrict__ xlr, const int* __restrict__ src,
                             const int* __restrict__ dst, const float* __restrict__ att,
                             float* __restrict__ exbuf, float* __restrict__ den) {
  constexpr int G = C / 8;
  constexpr int RS = 2 * C;
  int t = blockIdx.x * blockDim.x + threadIdx.x;
  int e = t / G;
  int lane = t - e * G;
  if (e >= N_EDGES) return;
  int s = src[e], d = dst[e];
  const float4* pl = (const float4*)(xlr + (size_t)s * RS) + lane * 2;
  const float4* pr = (const float4*)(xlr + (size_t)d * RS + C) + lane * 2;
  const float4* pa = (const float4*)(att) + lane * 2;
  float partial = 0.f;
#pragma unroll
  for (int i = 0; i < 2; ++i) {
    float4 l = pl[i];
    float4 r = pr[i];
    float4 a = pa[i];
    float v;
    v = l.x + r.x; v = v > 0.f ? v : NEG * v; partial += a.x * v;
    v = l.y + r.y; v = v > 0.f ? v : NEG * v; partial += a.y * v;
    v = l.z + r.z; v = v > 0.f ? v : NEG * v; partial += a.z * v;
    v = l.w + r.w; v = v > 0.f ? v : NEG * v; partial += a.w * v;
  }
#pragma unroll
  for (int off = G / 2; off > 0; off >>= 1) partial += __shfl_xor(partial, off, 64);
  if (lane == 0) {
    float ex = expf(partial);
    exbuf[e] = ex;
    atomicAdd(den + d, ex);
  }
}

// Edge pass B: acc[dst] += (ex/den[dst]) * xl[src]
template <int C>
__global__ void k_edge_accum(const float* __restrict__ xlr, const int* __restrict__ src,
                             const int* __restrict__ dst, const float* __restrict__ exbuf,
                             const float* __restrict__ den, float* __restrict__ acc) {
  constexpr int G = C / 8;
  constexpr int RS = 2 * C;
  int t = blockIdx.x * blockDim.x + threadIdx.x;
  int e = t / G;
  int lane = t - e * G;
  if (e >= N_EDGES) return;
  int s = src[e], d = dst[e];
  float coef = exbuf[e] / fmaxf(den[d], 1e-16f);
  const float4* pl = (const float4*)(xlr + (size_t)s * RS) + lane * 2;
  float* pa = acc + (size_t)d * C + lane * 8;
#pragma unroll
  for (int i = 0; i < 2; ++i) {
    float4 l = pl[i];
    atomicAdd(pa + i * 4 + 0, coef * l.x);
    atomicAdd(pa + i * 4 + 1, coef * l.y);
    atomicAdd(pa + i * 4 + 2, coef * l.z);
    atomicAdd(pa + i * 4 + 3, coef * l.w);
  }
}

// h = relu(acc + bias), in place.  cmask = C-1 (C power of 2)
__global__ void k_finalize(float* __restrict__ h, const float* __restrict__ bias, int cmask,
                           int total) {
  int t = blockIdx.x * blockDim.x + threadIdx.x;
  if (t >= total) return;
  float v = h[t] + bias[t & cmask];
  h[t] = v > 0.f ? v : 0.f;
}

// pooled[batch[n]] += h3[n], cnt[batch[n]] += 1
__global__ void k_pool(const float* __restrict__ h3, const int* __restrict__ batch,
                       float* __restrict__ pooled, float* __restrict__ cnt) {
  int t = blockIdx.x * blockDim.x + threadIdx.x;
  if (t >= N_NODES * HC2C) return;
  int n = t >> 5, c = t & 31;
  int b = batch[n];
  atomicAdd(pooled + b * HC2C + c, h3[t]);
  if (c == 0) atomicAdd(cnt + b, 1.0f);
}

// sx = relu(concat(h3[root], pooled/cnt) @ linW + linb)
__global__ void k_sx(const float* __restrict__ h3, const int* __restrict__ root,
                     const float* __restrict__ pooled, const float* __restrict__ cnt,
                     const float* __restrict__ linW, const float* __restrict__ linb,
                     float* __restrict__ sx) {
  int t = blockIdx.x * blockDim.x + threadIdx.x;
  if (t >= NB * HC2C) return;
  int b = t >> 5, j = t & 31;
  int r = root[b];
  float inv = 1.f / fmaxf(cnt[b], 1.0f);
  float a = linb[j];
  for (int c = 0; c < HC2C; ++c) a += h3[(size_t)r * HC2C + c] * linW[c * HC2C + j];
  for (int c = 0; c < HC2C; ++c) a += (pooled[b * HC2C + c] * inv) * linW[(HC2C + c) * HC2C + j];
  sx[t] = a > 0.f ? a : 0.f;
}

// info[b,i] = c1w0*x[root,i] + c1w1*x[root,i+1] + c1w2*x[root,i+2] + c1b
__global__ void k_info1(const float* __restrict__ X, const int* __restrict__ root,
                        const float* __restrict__ c1w, const float* __restrict__ c1b,
                        float* __restrict__ info) {
  constexpr int L = IN_F - 2;  // 254
  int t = blockIdx.x * blockDim.x + threadIdx.x;
  if (t >= NB * L) return;
  int b = t / L, i = t - (t / L) * L;
  const float* xr = X + (size_t)root[b] * IN_F;
  info[t] = c1w[0] * xr[i] + c1w[1] * xr[i + 1] + c1w[2] * xr[i + 2] + c1b[0];
}

// t1[j,b] = relu(c2W[j,:] . info[b,:] + c2b[j])   (128 x 64)
__global__ void k_info2(const float* __restrict__ info, const float* __restrict__ c2W,
                        const float* __restrict__ c2b, float* __restrict__ t1) {
  constexpr int L = IN_F - 2;
  int t = blockIdx.x * blockDim.x + threadIdx.x;
  if (t >= HC1C * NB) return;
  int j = t >> 6, b = t & 63;
  float a = c2b[j];
  for (int i = 0; i < L; ++i) a += c2W[j * L + i] * info[b * L + i];
  t1[t] = a > 0.f ? a : 0.f;
}

// t2[j,b] = relu(c3W[j,:] . t1[:,b] + c3b[j])   (64 x 64)
__global__ void k_info3(const float* __restrict__ t1, const float* __restrict__ c3W,
                        const float* __restrict__ c3b, float* __restrict__ t2) {
  int t = blockIdx.x * blockDim.x + threadIdx.x;
  if (t >= NB * NB) return;
  int j = t >> 6, b = t & 63;
  float a = c3b[j];
  for (int i = 0; i < HC1C; ++i) a += c3W[j * HC1C + i] * t1[i * NB + b];
  t2[t] = a > 0.f ? a : 0.f;
}

// tt[b,c] = relu(0.5*(t2[2c,b] + t2[2c+1,b]))
__global__ void k_info4(const float* __restrict__ t2, float* __restrict__ tt) {
  int t = blockIdx.x * blockDim.x + threadIdx.x;
  if (t >= NB * HC2C) return;
  int b = t >> 5, c = t & 31;
  float v = 0.5f * (t2[(2 * c) * NB + b] + t2[(2 * c + 1) * NB + b]);
  tt[b * HC2C + c] = v > 0.f ? v : 0.f;
}

// attention-combine + classifier, one thread per batch element
__global__ void k_final(const float* __restrict__ sx, const float* __restrict__ tt,
                        const float* __restrict__ aW1, const float* __restrict__ ab1,
                        const float* __restrict__ aW2, const float* __restrict__ mW1,
                        const float* __restrict__ mb1, const float* __restrict__ mW2,
                        const float* __restrict__ mb2, float* __restrict__ out) {
  int b = threadIdx.x;
  if (b >= NB) return;
  const float* e0 = sx + b * HC2C;
  const float* e1 = tt + b * HC2C;
  float w[2];
#pragma unroll
  for (int r = 0; r < 2; ++r) {
    const float* eb = (r == 0) ? e0 : e1;
    float acc = 0.f;
    for (int j = 0; j < 16; ++j) {
      float z = ab1[j];
      for (int c = 0; c < HC2C; ++c) z += eb[c] * aW1[c * 16 + j];
      acc += tanhf(z) * aW2[j];
    }
    w[r] = acc;
  }
  float mx = fmaxf(w[0], w[1]);
  float x0 = expf(w[0] - mx), x1 = expf(w[1] - mx);
  float inv = 1.f / (x0 + x1);
  float b0 = x0 * inv, b1 = x1 * inv;
  float t16[16];
  for (int j = 0; j < 16; ++j) {
    float z = mb1[j];
    for (int c = 0; c < HC2C; ++c) z += (b0 * e0[c] + b1 * e1[c]) * mW1[c * 16 + j];
    t16[j] = tanhf(z);
  }
  float l0 = mb2[0], l1 = mb2[1];
  for (int j = 0; j < 16; ++j) {
    l0 += t16[j] * mW2[j * 2 + 0];
    l1 += t16[j] * mW2[j * 2 + 1];
  }
  float m2 = fmaxf(l0, l1);
  float y0 = expf(l0 - m2), y1 = expf(l1 - m2);
  float is = 1.f / (y0 + y1);
  out[b * 2 + 0] = y0 * is;
  out[b * 2 + 1] = y1 * is;
}

// ---------------- launcher ----------------
extern "C" void kernel_launch(void* const* d_in, const int* in_sizes, int n_in, void* d_out,
                              int out_size, void* d_ws, size_t ws_size, hipStream_t stream) {
  if (ws_size < WS_FLOATS * sizeof(float)) return;  // workspace too small: bail visibly

  const float* s_x   = (const float*)d_in[0];
  const int*   edge  = (const int*)d_in[1];
  const int*   batch = (const int*)d_in[2];
  const int*   root  = (const int*)d_in[3];
  const float* Wv    = (const float*)d_in[8];
  const float* bv    = (const float*)d_in[9];
  const float* Wl1   = (const float*)d_in[10];
  const float* bl1   = (const float*)d_in[11];
  const float* Wr1   = (const float*)d_in[12];
  const float* br1   = (const float*)d_in[13];
  const float* att1  = (const float*)d_in[14];
  const float* bias1 = (const float*)d_in[15];
  const float* Wl2   = (const float*)d_in[16];
  const float* bl2   = (const float*)d_in[17];
  const float* Wr2   = (const float*)d_in[18];
  const float* br2   = (const float*)d_in[19];
  const float* att2  = (const float*)d_in[20];
  const float* bias2 = (const float*)d_in[21];
  const float* Wl3   = (const float*)d_in[22];
  const float* bl3   = (const float*)d_in[23];
  const float* Wr3   = (const float*)d_in[24];
  const float* br3   = (const float*)d_in[25];
  const float* att3  = (const float*)d_in[26];
  const float* bias3 = (const float*)d_in[27];
  const float* c1w   = (const float*)d_in[28];
  const float* c1b   = (const float*)d_in[29];
  const float* c2W   = (const float*)d_in[30];
  const float* c2b   = (const float*)d_in[31];
  const float* c3W   = (const float*)d_in[32];
  const float* c3b   = (const float*)d_in[33];
  const float* linW  = (const float*)d_in[34];
  const float* linb  = (const float*)d_in[35];
  const float* aW1   = (const float*)d_in[36];
  const float* ab1   = (const float*)d_in[37];
  const float* aW2   = (const float*)d_in[38];
  const float* mW1   = (const float*)d_in[39];
  const float* mb1   = (const float*)d_in[40];
  const float* mW2   = (const float*)d_in[41];
  const float* mb2   = (const float*)d_in[42];

  const int* src = edge;
  const int* dst = edge + N_EDGES;

  float* ws   = (float*)d_ws;
  float* WcL  = ws + OFF_WCL;
  float* WcR  = ws + OFF_WCR;
  float* bcL  = ws + OFF_BCL;
  float* bcR  = ws + OFF_BCR;
  float* xlr  = ws + OFF_XLR;
  float* hbuf = ws + OFF_H;
  float* exb  = ws + OFF_EX;
  float* den  = ws + OFF_DEN;
  float* pooled = ws + OFF_POOLED;
  float* cnt  = ws + OFF_CNT;
  float* sx   = ws + OFF_SX;
  float* info = ws + OFF_INFO;
  float* t1   = ws + OFF_T1;
  float* t2   = ws + OFF_T2;
  float* tt   = ws + OFF_TT;
  float* out  = (float*)d_out;

  // fold Wv into layer-1 projections
  k_wcomb<<<(IN_F * HC1C + 255) / 256, 256, 0, stream>>>(Wv, Wl1, Wr1, WcL, WcR);
  k_bcomb<<<1, HC1C, 0, stream>>>(bv, Wl1, bl1, Wr1, br1, bcL, bcR);

  // ---- GAT layer 1 (C=128, K=256) ----
  k_gemm_lr<8, 256, 128><<<N_NODES / 8, 128, 0, stream>>>(s_x, WcL, bcL, WcR, bcR, xlr);
  hipMemsetAsync(den, 0, N_NODES * sizeof(float), stream);
  hipMemsetAsync(hbuf, 0, (size_t)N_NODES * 128 * sizeof(float), stream);
  k_edge_score<128><<<N_EDGES * 16 / 256, 256, 0, stream>>>(xlr, src, dst, att1, exb, den);
  k_edge_accum<128><<<N_EDGES * 16 / 256, 256, 0, stream>>>(xlr, src, dst, exb, den, hbuf);
  k_finalize<<<N_NODES * 128 / 256, 256, 0, stream>>>(hbuf, bias1, 127, N_NODES * 128);

  // ---- GAT layer 2 (C=64, K=128) ----
  k_gemm_lr<8, 128, 64><<<N_NODES / 8, 64, 0, stream>>>(hbuf, Wl2, bl2, Wr2, br2, xlr);
  hipMemsetAsync(den, 0, N_NODES * sizeof(float), stream);
  hipMemsetAsync(hbuf, 0, (size_t)N_NODES * 64 * sizeof(float), stream);
  k_edge_score<64><<<N_EDGES * 8 / 256, 256, 0, stream>>>(xlr, src, dst, att2, exb, den);
  k_edge_accum<64><<<N_EDGES * 8 / 256, 256, 0, stream>>>(xlr, src, dst, exb, den, hbuf);
  k_finalize<<<N_NODES * 64 / 256, 256, 0, stream>>>(hbuf, bias2, 63, N_NODES * 64);

  // ---- GAT layer 3 (C=32, K=64) ----
  k_gemm_lr<8, 64, 32><<<N_NODES / 8, 32, 0, stream>>>(hbuf, Wl3, bl3, Wr3, br3, xlr);
  hipMemsetAsync(den, 0, N_NODES * sizeof(float), stream);
  hipMemsetAsync(hbuf, 0, (size_t)N_NODES * 32 * sizeof(float), stream);
  k_edge_score<32><<<N_EDGES * 4 / 256, 256, 0, stream>>>(xlr, src, dst, att3, exb, den);
  k_edge_accum<32><<<N_EDGES * 4 / 256, 256, 0, stream>>>(xlr, src, dst, exb, den, hbuf);
  k_finalize<<<N_NODES * 32 / 256, 256, 0, stream>>>(hbuf, bias3, 31, N_NODES * 32);

  // ---- pooling + root concat + lin ----
  hipMemsetAsync(pooled, 0, (NB * HC2C + NB) * sizeof(float), stream);  // pooled + cnt
  k_pool<<<N_NODES * 32 / 256, 256, 0, stream>>>(hbuf, batch, pooled, cnt);
  k_sx<<<(NB * HC2C + 255) / 256, 256, 0, stream>>>(hbuf, root, pooled, cnt, linW, linb, sx);

  // ---- info path ----
  k_info1<<<(NB * (IN_F - 2) + 255) / 256, 256, 0, stream>>>(s_x, root, c1w, c1b, info);
  k_info2<<<(HC1C * NB + 255) / 256, 256, 0, stream>>>(info, c2W, c2b, t1);
  k_info3<<<(NB * NB + 255) / 256, 256, 0, stream>>>(t1, c3W, c3b, t2);
  k_info4<<<(NB * HC2C + 255) / 256, 256, 0, stream>>>(t2, tt);

  // ---- attention combine + classifier ----
  k_final<<<1, NB, 0, stream>>>(sx, tt, aW1, ab1, aW2, mW1, mb1, mW2, mb2, out);
}

// Round 2
// 1539.392 us; speedup vs baseline: 4.1973x; 4.1973x over previous
//
#include <hip/hip_runtime.h>
#include <hip/hip_bf16.h>
#include <math.h>

// ---------------- problem constants ----------------
constexpr int N_NODES = 100000;
constexpr int N_EDGES = 800000;
constexpr int NB      = 64;
constexpr int IN_F    = 256;
constexpr int HC1C    = 128;
constexpr int HC2C    = 32;
constexpr int SA_D    = 350;
constexpr float NEG   = 0.2f;

constexpr int SCAN_NBLK = (N_NODES + 255) / 256;  // 391

// ---------------- workspace layout (float-sized slots; int regions cast) ----
constexpr size_t OFF_WCL    = 0;                                   // 256*128
constexpr size_t OFF_WCR    = OFF_WCL + (size_t)IN_F * HC1C;
constexpr size_t OFF_BCL    = OFF_WCR + (size_t)IN_F * HC1C;       // 128
constexpr size_t OFF_BCR    = OFF_BCL + HC1C;                      // 128
constexpr size_t OFF_XLR    = OFF_BCR + HC1C;                      // N*256
constexpr size_t OFF_H      = OFF_XLR + (size_t)N_NODES * 256;     // N*128
constexpr size_t OFF_DEG    = OFF_H + (size_t)N_NODES * 128;       // N ints
constexpr size_t OFF_ROWPTR = OFF_DEG + N_NODES;                   // N+1 ints
constexpr size_t OFF_CURSOR = OFF_ROWPTR + N_NODES + 1;            // N ints
constexpr size_t OFF_BLKS   = OFF_CURSOR + N_NODES;                // 512 ints
constexpr size_t OFF_BLKO   = OFF_BLKS + 512;                      // 512 ints
constexpr size_t OFF_CSRSRC = OFF_BLKO + 512;                      // E ints
constexpr size_t OFF_POOLED = OFF_CSRSRC + N_EDGES;                // 64*32
constexpr size_t OFF_CNT    = OFF_POOLED + NB * HC2C;              // 64
constexpr size_t OFF_SX     = OFF_CNT + NB;                        // 64*32
constexpr size_t OFF_INFO   = OFF_SX + NB * HC2C;                  // 64*254
constexpr size_t OFF_T1     = OFF_INFO + (size_t)NB * (IN_F - 2);  // 128*64
constexpr size_t OFF_T2     = OFF_T1 + (size_t)HC1C * NB;          // 64*64
constexpr size_t OFF_TT     = OFF_T2 + (size_t)NB * NB;            // 64*32
constexpr size_t WS_FLOATS  = OFF_TT + NB * HC2C;

// ---------------- weight-fold kernels ----------------
__global__ void k_wcomb(const float* __restrict__ Wv, const float* __restrict__ Wl1,
                        const float* __restrict__ Wr1, float* __restrict__ WcL,
                        float* __restrict__ WcR) {
  int t = blockIdx.x * blockDim.x + threadIdx.x;
  if (t >= IN_F * HC1C) return;
  int i = t / HC1C, j = t - (t / HC1C) * HC1C;
  float al = 0.f, ar = 0.f;
  for (int k = 0; k < SA_D; ++k) {
    float wv = Wv[i * SA_D + k];
    al += wv * Wl1[k * HC1C + j];
    ar += wv * Wr1[k * HC1C + j];
  }
  WcL[t] = al;
  WcR[t] = ar;
}

__global__ void k_bcomb(const float* __restrict__ bv, const float* __restrict__ Wl1,
                        const float* __restrict__ bl1, const float* __restrict__ Wr1,
                        const float* __restrict__ br1, float* __restrict__ bcL,
                        float* __restrict__ bcR) {
  int j = threadIdx.x;
  if (j >= HC1C) return;
  float al = bl1[j], ar = br1[j];
  for (int k = 0; k < SA_D; ++k) {
    al += bv[k] * Wl1[k * HC1C + j];
    ar += bv[k] * Wr1[k * HC1C + j];
  }
  bcL[j] = al;
  bcR[j] = ar;
}

// ---------------- CSR build ----------------
__global__ void k_hist(const int* __restrict__ dst, int* __restrict__ deg) {
  int e = blockIdx.x * blockDim.x + threadIdx.x;
  if (e < N_EDGES) atomicAdd(deg + dst[e], 1);
}

// per-block exclusive scan; row_ptr gets block-local exclusive, blk_sum gets block total
__global__ void k_scan_local(const int* __restrict__ deg, int* __restrict__ row_ptr,
                             int* __restrict__ blk_sum) {
  __shared__ int sh[256];
  int t = threadIdx.x;
  int i = blockIdx.x * 256 + t;
  int v = (i < N_NODES) ? deg[i] : 0;
  sh[t] = v;
  __syncthreads();
  for (int off = 1; off < 256; off <<= 1) {
    int add = (t >= off) ? sh[t - off] : 0;
    __syncthreads();
    sh[t] += add;
    __syncthreads();
  }
  if (i < N_NODES) row_ptr[i] = sh[t] - v;  // exclusive
  if (t == 255) blk_sum[blockIdx.x] = sh[255];
}

// single-block exclusive scan of block sums (SCAN_NBLK <= 512)
__global__ void k_scan_blk(const int* __restrict__ blk_sum, int* __restrict__ blk_off) {
  __shared__ int sh[512];
  int t = threadIdx.x;
  int v = (t < SCAN_NBLK) ? blk_sum[t] : 0;
  sh[t] = v;
  __syncthreads();
  for (int off = 1; off < 512; off <<= 1) {
    int add = (t >= off) ? sh[t - off] : 0;
    __syncthreads();
    sh[t] += add;
    __syncthreads();
  }
  blk_off[t] = sh[t] - v;  // exclusive
}

__global__ void k_scan_add(int* __restrict__ row_ptr, const int* __restrict__ blk_off,
                           int* __restrict__ cursor) {
  int i = blockIdx.x * blockDim.x + threadIdx.x;
  if (i < N_NODES) {
    int v = row_ptr[i] + blk_off[i >> 8];
    row_ptr[i] = v;
    cursor[i] = v;
  }
  if (i == 0) row_ptr[N_NODES] = N_EDGES;
}

__global__ void k_fill(const int* __restrict__ src, const int* __restrict__ dst,
                       int* __restrict__ cursor, int* __restrict__ csr_src) {
  int e = blockIdx.x * blockDim.x + threadIdx.x;
  if (e >= N_EDGES) return;
  int pos = atomicAdd(cursor + dst[e], 1);
  csr_src[pos] = src[e];
}

// ---------------- dense GEMM producing [xl | xr] ----------------
template <int TN, int K, int C>
__global__ __launch_bounds__(C) void k_gemm_lr(const float* __restrict__ x,
                                               const float* __restrict__ Wl,
                                               const float* __restrict__ bl,
                                               const float* __restrict__ Wr,
                                               const float* __restrict__ br,
                                               float* __restrict__ out) {
  __shared__ __align__(16) float xs[K * TN];  // transposed tile: xs[k*TN + r]
  const int m = threadIdx.x;
  const size_t n0 = (size_t)blockIdx.x * TN;
  for (int i = m; i < TN * K; i += C) {
    int r = i / K;
    int k = i - r * K;
    xs[k * TN + r] = x[n0 * K + i];
  }
  __syncthreads();
  float accL[TN], accR[TN];
#pragma unroll
  for (int r = 0; r < TN; ++r) { accL[r] = 0.f; accR[r] = 0.f; }
#pragma unroll 4
  for (int k = 0; k < K; ++k) {
    float wl = Wl[(size_t)k * C + m];
    float wr = Wr[(size_t)k * C + m];
    const float4* xv = (const float4*)(xs + k * TN);
    float4 a = xv[0];
    float4 b4 = xv[1];
    float xr8[8] = {a.x, a.y, a.z, a.w, b4.x, b4.y, b4.z, b4.w};
#pragma unroll
    for (int r = 0; r < TN; ++r) {
      accL[r] += xr8[r] * wl;
      accR[r] += xr8[r] * wr;
    }
  }
#pragma unroll
  for (int r = 0; r < TN; ++r) {
    out[(n0 + r) * (2 * C) + m]     = accL[r] + bl[m];
    out[(n0 + r) * (2 * C) + C + m] = accR[r] + br[m];
  }
}

// ---------------- fused per-node GAT edge pass ----------------
// group of G = C/4 lanes owns one destination node; single sweep over its
// incoming edges with online (max-free) softmax; epilogue bias+relu fused.
template <int C>
__global__ void k_gat(const float* __restrict__ xlr, const int* __restrict__ row_ptr,
                      const int* __restrict__ csr_src, const float* __restrict__ att,
                      const float* __restrict__ bias, float* __restrict__ h) {
  constexpr int G = C / 4;
  constexpr int RS = 2 * C;
  int t = blockIdx.x * blockDim.x + threadIdx.x;
  int d = t / G;
  int lane = t - d * G;
  if (d >= N_NODES) return;
  const float4 xr = *(const float4*)(xlr + (size_t)d * RS + C + lane * 4);
  const float4 a4 = *(const float4*)(att + lane * 4);
  float4 acc = {0.f, 0.f, 0.f, 0.f};
  float den = 0.f;
  const int e0 = row_ptr[d], e1 = row_ptr[d + 1];
  for (int i = e0; i < e1; ++i) {
    int s = csr_src[i];
    float4 xl = *(const float4*)(xlr + (size_t)s * RS + lane * 4);
    float v, p = 0.f;
    v = xl.x + xr.x; v = v > 0.f ? v : NEG * v; p += a4.x * v;
    v = xl.y + xr.y; v = v > 0.f ? v : NEG * v; p += a4.y * v;
    v = xl.z + xr.z; v = v > 0.f ? v : NEG * v; p += a4.z * v;
    v = xl.w + xr.w; v = v > 0.f ? v : NEG * v; p += a4.w * v;
#pragma unroll
    for (int off = G / 2; off > 0; off >>= 1) p += __shfl_xor(p, off, 64);
    float ex = expf(p);
    den += ex;
    acc.x += ex * xl.x;
    acc.y += ex * xl.y;
    acc.z += ex * xl.z;
    acc.w += ex * xl.w;
  }
  float inv = 1.f / fmaxf(den, 1e-16f);
  const float4 b4 = *(const float4*)(bias + lane * 4);
  float4 o;
  o.x = fmaxf(acc.x * inv + b4.x, 0.f);
  o.y = fmaxf(acc.y * inv + b4.y, 0.f);
  o.z = fmaxf(acc.z * inv + b4.z, 0.f);
  o.w = fmaxf(acc.w * inv + b4.w, 0.f);
  *(float4*)(h + (size_t)d * C + lane * 4) = o;
}

// ---------------- tail ----------------
__global__ void k_pool(const float* __restrict__ h3, const int* __restrict__ batch,
                       float* __restrict__ pooled, float* __restrict__ cnt) {
  int t = blockIdx.x * blockDim.x + threadIdx.x;
  if (t >= N_NODES * HC2C) return;
  int n = t >> 5, c = t & 31;
  int b = batch[n];
  atomicAdd(pooled + b * HC2C + c, h3[t]);
  if (c == 0) atomicAdd(cnt + b, 1.0f);
}

__global__ void k_sx(const float* __restrict__ h3, const int* __restrict__ root,
                     const float* __restrict__ pooled, const float* __restrict__ cnt,
                     const float* __restrict__ linW, const float* __restrict__ linb,
                     float* __restrict__ sx) {
  int t = blockIdx.x * blockDim.x + threadIdx.x;
  if (t >= NB * HC2C) return;
  int b = t >> 5, j = t & 31;
  int r = root[b];
  float inv = 1.f / fmaxf(cnt[b], 1.0f);
  float a = linb[j];
  for (int c = 0; c < HC2C; ++c) a += h3[(size_t)r * HC2C + c] * linW[c * HC2C + j];
  for (int c = 0; c < HC2C; ++c) a += (pooled[b * HC2C + c] * inv) * linW[(HC2C + c) * HC2C + j];
  sx[t] = a > 0.f ? a : 0.f;
}

__global__ void k_info1(const float* __restrict__ X, const int* __restrict__ root,
                        const float* __restrict__ c1w, const float* __restrict__ c1b,
                        float* __restrict__ info) {
  constexpr int L = IN_F - 2;
  int t = blockIdx.x * blockDim.x + threadIdx.x;
  if (t >= NB * L) return;
  int b = t / L, i = t - (t / L) * L;
  const float* xr = X + (size_t)root[b] * IN_F;
  info[t] = c1w[0] * xr[i] + c1w[1] * xr[i + 1] + c1w[2] * xr[i + 2] + c1b[0];
}

__global__ void k_info2(const float* __restrict__ info, const float* __restrict__ c2W,
                        const float* __restrict__ c2b, float* __restrict__ t1) {
  constexpr int L = IN_F - 2;
  int t = blockIdx.x * blockDim.x + threadIdx.x;
  if (t >= HC1C * NB) return;
  int j = t >> 6, b = t & 63;
  float a = c2b[j];
  for (int i = 0; i < L; ++i) a += c2W[j * L + i] * info[b * L + i];
  t1[t] = a > 0.f ? a : 0.f;
}

__global__ void k_info3(const float* __restrict__ t1, const float* __restrict__ c3W,
                        const float* __restrict__ c3b, float* __restrict__ t2) {
  int t = blockIdx.x * blockDim.x + threadIdx.x;
  if (t >= NB * NB) return;
  int j = t >> 6, b = t & 63;
  float a = c3b[j];
  for (int i = 0; i < HC1C; ++i) a += c3W[j * HC1C + i] * t1[i * NB + b];
  t2[t] = a > 0.f ? a : 0.f;
}

__global__ void k_info4(const float* __restrict__ t2, float* __restrict__ tt) {
  int t = blockIdx.x * blockDim.x + threadIdx.x;
  if (t >= NB * HC2C) return;
  int b = t >> 5, c = t & 31;
  float v = 0.5f * (t2[(2 * c) * NB + b] + t2[(2 * c + 1) * NB + b]);
  tt[b * HC2C + c] = v > 0.f ? v : 0.f;
}

__global__ void k_final(const float* __restrict__ sx, const float* __restrict__ tt,
                        const float* __restrict__ aW1, const float* __restrict__ ab1,
                        const float* __restrict__ aW2, const float* __restrict__ mW1,
                        const float* __restrict__ mb1, const float* __restrict__ mW2,
                        const float* __restrict__ mb2, float* __restrict__ out) {
  int b = threadIdx.x;
  if (b >= NB) return;
  const float* e0 = sx + b * HC2C;
  const float* e1 = tt + b * HC2C;
  float w[2];
#pragma unroll
  for (int r = 0; r < 2; ++r) {
    const float* eb = (r == 0) ? e0 : e1;
    float acc = 0.f;
    for (int j = 0; j < 16; ++j) {
      float z = ab1[j];
      for (int c = 0; c < HC2C; ++c) z += eb[c] * aW1[c * 16 + j];
      acc += tanhf(z) * aW2[j];
    }
    w[r] = acc;
  }
  float mx = fmaxf(w[0], w[1]);
  float x0 = expf(w[0] - mx), x1 = expf(w[1] - mx);
  float inv = 1.f / (x0 + x1);
  float b0 = x0 * inv, b1 = x1 * inv;
  float t16[16];
  for (int j = 0; j < 16; ++j) {
    float z = mb1[j];
    for (int c = 0; c < HC2C; ++c) z += (b0 * e0[c] + b1 * e1[c]) * mW1[c * 16 + j];
    t16[j] = tanhf(z);
  }
  float l0 = mb2[0], l1 = mb2[1];
  for (int j = 0; j < 16; ++j) {
    l0 += t16[j] * mW2[j * 2 + 0];
    l1 += t16[j] * mW2[j * 2 + 1];
  }
  float m2 = fmaxf(l0, l1);
  float y0 = expf(l0 - m2), y1 = expf(l1 - m2);
  float is = 1.f / (y0 + y1);
  out[b * 2 + 0] = y0 * is;
  out[b * 2 + 1] = y1 * is;
}

// ---------------- launcher ----------------
extern "C" void kernel_launch(void* const* d_in, const int* in_sizes, int n_in, void* d_out,
                              int out_size, void* d_ws, size_t ws_size, hipStream_t stream) {
  if (ws_size < WS_FLOATS * sizeof(float)) return;

  const float* s_x   = (const float*)d_in[0];
  const int*   edge  = (const int*)d_in[1];
  const int*   batch = (const int*)d_in[2];
  const int*   root  = (const int*)d_in[3];
  const float* Wv    = (const float*)d_in[8];
  const float* bv    = (const float*)d_in[9];
  const float* Wl1   = (const float*)d_in[10];
  const float* bl1   = (const float*)d_in[11];
  const float* Wr1   = (const float*)d_in[12];
  const float* br1   = (const float*)d_in[13];
  const float* att1  = (const float*)d_in[14];
  const float* bias1 = (const float*)d_in[15];
  const float* Wl2   = (const float*)d_in[16];
  const float* bl2   = (const float*)d_in[17];
  const float* Wr2   = (const float*)d_in[18];
  const float* br2   = (const float*)d_in[19];
  const float* att2  = (const float*)d_in[20];
  const float* bias2 = (const float*)d_in[21];
  const float* Wl3   = (const float*)d_in[22];
  const float* bl3   = (const float*)d_in[23];
  const float* Wr3   = (const float*)d_in[24];
  const float* br3   = (const float*)d_in[25];
  const float* att3  = (const float*)d_in[26];
  const float* bias3 = (const float*)d_in[27];
  const float* c1w   = (const float*)d_in[28];
  const float* c1b   = (const float*)d_in[29];
  const float* c2W   = (const float*)d_in[30];
  const float* c2b   = (const float*)d_in[31];
  const float* c3W   = (const float*)d_in[32];
  const float* c3b   = (const float*)d_in[33];
  const float* linW  = (const float*)d_in[34];
  const float* linb  = (const float*)d_in[35];
  const float* aW1   = (const float*)d_in[36];
  const float* ab1   = (const float*)d_in[37];
  const float* aW2   = (const float*)d_in[38];
  const float* mW1   = (const float*)d_in[39];
  const float* mb1   = (const float*)d_in[40];
  const float* mW2   = (const float*)d_in[41];
  const float* mb2   = (const float*)d_in[42];

  const int* src = edge;
  const int* dst = edge + N_EDGES;

  float* ws      = (float*)d_ws;
  float* WcL     = ws + OFF_WCL;
  float* WcR     = ws + OFF_WCR;
  float* bcL     = ws + OFF_BCL;
  float* bcR     = ws + OFF_BCR;
  float* xlr     = ws + OFF_XLR;
  float* hbuf    = ws + OFF_H;
  int*   deg     = (int*)(ws + OFF_DEG);
  int*   row_ptr = (int*)(ws + OFF_ROWPTR);
  int*   cursor  = (int*)(ws + OFF_CURSOR);
  int*   blks    = (int*)(ws + OFF_BLKS);
  int*   blko    = (int*)(ws + OFF_BLKO);
  int*   csr_src = (int*)(ws + OFF_CSRSRC);
  float* pooled  = ws + OFF_POOLED;
  float* cnt     = ws + OFF_CNT;
  float* sx      = ws + OFF_SX;
  float* info    = ws + OFF_INFO;
  float* t1      = ws + OFF_T1;
  float* t2      = ws + OFF_T2;
  float* tt      = ws + OFF_TT;
  float* out     = (float*)d_out;

  // ---- CSR build (by dst) ----
  hipMemsetAsync(deg, 0, N_NODES * sizeof(int), stream);
  k_hist<<<(N_EDGES + 255) / 256, 256, 0, stream>>>(dst, deg);
  k_scan_local<<<SCAN_NBLK, 256, 0, stream>>>(deg, row_ptr, blks);
  k_scan_blk<<<1, 512, 0, stream>>>(blks, blko);
  k_scan_add<<<SCAN_NBLK, 256, 0, stream>>>(row_ptr, blko, cursor);
  k_fill<<<(N_EDGES + 255) / 256, 256, 0, stream>>>(src, dst, cursor, csr_src);

  // ---- fold Wv into layer-1 projections ----
  k_wcomb<<<(IN_F * HC1C + 255) / 256, 256, 0, stream>>>(Wv, Wl1, Wr1, WcL, WcR);
  k_bcomb<<<1, HC1C, 0, stream>>>(bv, Wl1, bl1, Wr1, br1, bcL, bcR);

  // ---- GAT layer 1 (C=128, K=256) ----
  k_gemm_lr<8, 256, 128><<<N_NODES / 8, 128, 0, stream>>>(s_x, WcL, bcL, WcR, bcR, xlr);
  k_gat<128><<<(N_NODES * 32 + 255) / 256, 256, 0, stream>>>(xlr, row_ptr, csr_src, att1,
                                                             bias1, hbuf);

  // ---- GAT layer 2 (C=64, K=128) ----
  k_gemm_lr<8, 128, 64><<<N_NODES / 8, 64, 0, stream>>>(hbuf, Wl2, bl2, Wr2, br2, xlr);
  k_gat<64><<<(N_NODES * 16 + 255) / 256, 256, 0, stream>>>(xlr, row_ptr, csr_src, att2,
                                                            bias2, hbuf);

  // ---- GAT layer 3 (C=32, K=64) ----
  k_gemm_lr<8, 64, 32><<<N_NODES / 8, 32, 0, stream>>>(hbuf, Wl3, bl3, Wr3, br3, xlr);
  k_gat<32><<<(N_NODES * 8 + 255) / 256, 256, 0, stream>>>(xlr, row_ptr, csr_src, att3,
                                                           bias3, hbuf);

  // ---- pooling + root concat + lin ----
  hipMemsetAsync(pooled, 0, (NB * HC2C + NB) * sizeof(float), stream);
  k_pool<<<(N_NODES * 32 + 255) / 256, 256, 0, stream>>>(hbuf, batch, pooled, cnt);
  k_sx<<<(NB * HC2C + 255) / 256, 256, 0, stream>>>(hbuf, root, pooled, cnt, linW, linb, sx);

  // ---- info path ----
  k_info1<<<(NB * (IN_F - 2) + 255) / 256, 256, 0, stream>>>(s_x, root, c1w, c1b, info);
  k_info2<<<(HC1C * NB + 255) / 256, 256, 0, stream>>>(info, c2W, c2b, t1);
  k_info3<<<(NB * NB + 255) / 256, 256, 0, stream>>>(t1, c3W, c3b, t2);
  k_info4<<<(NB * HC2C + 255) / 256, 256, 0, stream>>>(t2, tt);

  // ---- attention combine + classifier ----
  k_final<<<1, NB, 0, stream>>>(sx, tt, aW1, ab1, aW2, mW1, mb1, mW2, mb2, out);
}

// Round 3
// 876.417 us; speedup vs baseline: 7.3725x; 1.7565x over previous
//
#include <hip/hip_runtime.h>
#include <hip/hip_bf16.h>
#include <math.h>

// ---------------- problem constants ----------------
constexpr int N_NODES = 100000;
constexpr int N_EDGES = 800000;
constexpr int NB      = 64;
constexpr int IN_F    = 256;
constexpr int HC1C    = 128;
constexpr int HC2C    = 32;
constexpr int SA_D    = 350;
constexpr float NEG   = 0.2f;

constexpr int SCAN_NBLK = (N_NODES + 255) / 256;  // 391

// ---------------- workspace layout (float-sized slots; int regions cast) ----
constexpr size_t OFF_WCL    = 0;                                   // 256*128
constexpr size_t OFF_WCR    = OFF_WCL + (size_t)IN_F * HC1C;
constexpr size_t OFF_BCL    = OFF_WCR + (size_t)IN_F * HC1C;       // 128
constexpr size_t OFF_BCR    = OFF_BCL + HC1C;                      // 128
constexpr size_t OFF_XLR    = OFF_BCR + HC1C;                      // N*256
constexpr size_t OFF_H      = OFF_XLR + (size_t)N_NODES * 256;     // N*128
constexpr size_t OFF_DEG    = OFF_H + (size_t)N_NODES * 128;       // N ints
constexpr size_t OFF_ROWPTR = OFF_DEG + N_NODES;                   // N+1 ints
constexpr size_t OFF_CURSOR = OFF_ROWPTR + N_NODES + 1;            // N ints
constexpr size_t OFF_BLKS   = OFF_CURSOR + N_NODES;                // 512 ints
constexpr size_t OFF_BLKO   = OFF_BLKS + 512;                      // 512 ints
constexpr size_t OFF_CSRSRC = OFF_BLKO + 512;                      // E ints
constexpr size_t OFF_POOLED = OFF_CSRSRC + N_EDGES;                // 64*32
constexpr size_t OFF_CNT    = OFF_POOLED + NB * HC2C;              // 64
constexpr size_t OFF_SX     = OFF_CNT + NB;                        // 64*32
constexpr size_t OFF_INFO   = OFF_SX + NB * HC2C;                  // 64*254
constexpr size_t OFF_T1     = OFF_INFO + (size_t)NB * (IN_F - 2);  // 128*64
constexpr size_t OFF_T2     = OFF_T1 + (size_t)HC1C * NB;          // 64*64
constexpr size_t OFF_TT     = OFF_T2 + (size_t)NB * NB;            // 64*32
constexpr size_t WS_FLOATS  = OFF_TT + NB * HC2C;

// ---------------- weight-fold kernels ----------------
__global__ void k_wcomb(const float* __restrict__ Wv, const float* __restrict__ Wl1,
                        const float* __restrict__ Wr1, float* __restrict__ WcL,
                        float* __restrict__ WcR) {
  int t = blockIdx.x * blockDim.x + threadIdx.x;
  if (t >= IN_F * HC1C) return;
  int i = t / HC1C, j = t - (t / HC1C) * HC1C;
  float al = 0.f, ar = 0.f;
  for (int k = 0; k < SA_D; ++k) {
    float wv = Wv[i * SA_D + k];
    al += wv * Wl1[k * HC1C + j];
    ar += wv * Wr1[k * HC1C + j];
  }
  WcL[t] = al;
  WcR[t] = ar;
}

__global__ void k_bcomb(const float* __restrict__ bv, const float* __restrict__ Wl1,
                        const float* __restrict__ bl1, const float* __restrict__ Wr1,
                        const float* __restrict__ br1, float* __restrict__ bcL,
                        float* __restrict__ bcR) {
  int j = threadIdx.x;
  if (j >= HC1C) return;
  float al = bl1[j], ar = br1[j];
  for (int k = 0; k < SA_D; ++k) {
    al += bv[k] * Wl1[k * HC1C + j];
    ar += bv[k] * Wr1[k * HC1C + j];
  }
  bcL[j] = al;
  bcR[j] = ar;
}

// ---------------- CSR build ----------------
__global__ void k_hist(const int* __restrict__ dst, int* __restrict__ deg) {
  int e = blockIdx.x * blockDim.x + threadIdx.x;
  if (e < N_EDGES) atomicAdd(deg + dst[e], 1);
}

__global__ void k_scan_local(const int* __restrict__ deg, int* __restrict__ row_ptr,
                             int* __restrict__ blk_sum) {
  __shared__ int sh[256];
  int t = threadIdx.x;
  int i = blockIdx.x * 256 + t;
  int v = (i < N_NODES) ? deg[i] : 0;
  sh[t] = v;
  __syncthreads();
  for (int off = 1; off < 256; off <<= 1) {
    int add = (t >= off) ? sh[t - off] : 0;
    __syncthreads();
    sh[t] += add;
    __syncthreads();
  }
  if (i < N_NODES) row_ptr[i] = sh[t] - v;  // exclusive
  if (t == 255) blk_sum[blockIdx.x] = sh[255];
}

__global__ void k_scan_blk(const int* __restrict__ blk_sum, int* __restrict__ blk_off) {
  __shared__ int sh[512];
  int t = threadIdx.x;
  int v = (t < SCAN_NBLK) ? blk_sum[t] : 0;
  sh[t] = v;
  __syncthreads();
  for (int off = 1; off < 512; off <<= 1) {
    int add = (t >= off) ? sh[t - off] : 0;
    __syncthreads();
    sh[t] += add;
    __syncthreads();
  }
  blk_off[t] = sh[t] - v;  // exclusive
}

__global__ void k_scan_add(int* __restrict__ row_ptr, const int* __restrict__ blk_off,
                           int* __restrict__ cursor) {
  int i = blockIdx.x * blockDim.x + threadIdx.x;
  if (i < N_NODES) {
    int v = row_ptr[i] + blk_off[i >> 8];
    row_ptr[i] = v;
    cursor[i] = v;
  }
  if (i == 0) row_ptr[N_NODES] = N_EDGES;
}

__global__ void k_fill(const int* __restrict__ src, const int* __restrict__ dst,
                       int* __restrict__ cursor, int* __restrict__ csr_src) {
  int e = blockIdx.x * blockDim.x + threadIdx.x;
  if (e >= N_EDGES) return;
  int pos = atomicAdd(cursor + dst[e], 1);
  csr_src[pos] = src[e];
}

// ---------------- dense GEMM producing [xl | xr] ----------------
template <int TN, int K, int C>
__global__ __launch_bounds__(C) void k_gemm_lr(const float* __restrict__ x,
                                               const float* __restrict__ Wl,
                                               const float* __restrict__ bl,
                                               const float* __restrict__ Wr,
                                               const float* __restrict__ br,
                                               float* __restrict__ out) {
  __shared__ __align__(16) float xs[K * TN];  // transposed tile: xs[k*TN + r]
  const int m = threadIdx.x;
  const size_t n0 = (size_t)blockIdx.x * TN;
  for (int i = m; i < TN * K; i += C) {
    int r = i / K;
    int k = i - r * K;
    xs[k * TN + r] = x[n0 * K + i];
  }
  __syncthreads();
  float accL[TN], accR[TN];
#pragma unroll
  for (int r = 0; r < TN; ++r) { accL[r] = 0.f; accR[r] = 0.f; }
#pragma unroll 4
  for (int k = 0; k < K; ++k) {
    float wl = Wl[(size_t)k * C + m];
    float wr = Wr[(size_t)k * C + m];
    const float4* xv = (const float4*)(xs + k * TN);
    float4 a = xv[0];
    float4 b4 = xv[1];
    float xr8[8] = {a.x, a.y, a.z, a.w, b4.x, b4.y, b4.z, b4.w};
#pragma unroll
    for (int r = 0; r < TN; ++r) {
      accL[r] += xr8[r] * wl;
      accR[r] += xr8[r] * wr;
    }
  }
#pragma unroll
  for (int r = 0; r < TN; ++r) {
    out[(n0 + r) * (2 * C) + m]     = accL[r] + bl[m];
    out[(n0 + r) * (2 * C) + C + m] = accR[r] + br[m];
  }
}

// ---------------- fused per-node GAT edge pass ----------------
template <int C>
__global__ void k_gat(const float* __restrict__ xlr, const int* __restrict__ row_ptr,
                      const int* __restrict__ csr_src, const float* __restrict__ att,
                      const float* __restrict__ bias, float* __restrict__ h) {
  constexpr int G = C / 4;
  constexpr int RS = 2 * C;
  int t = blockIdx.x * blockDim.x + threadIdx.x;
  int d = t / G;
  int lane = t - d * G;
  if (d >= N_NODES) return;
  const float4 xr = *(const float4*)(xlr + (size_t)d * RS + C + lane * 4);
  const float4 a4 = *(const float4*)(att + lane * 4);
  float4 acc = {0.f, 0.f, 0.f, 0.f};
  float den = 0.f;
  const int e0 = row_ptr[d], e1 = row_ptr[d + 1];
  for (int i = e0; i < e1; ++i) {
    int s = csr_src[i];
    float4 xl = *(const float4*)(xlr + (size_t)s * RS + lane * 4);
    float v, p = 0.f;
    v = xl.x + xr.x; v = v > 0.f ? v : NEG * v; p += a4.x * v;
    v = xl.y + xr.y; v = v > 0.f ? v : NEG * v; p += a4.y * v;
    v = xl.z + xr.z; v = v > 0.f ? v : NEG * v; p += a4.z * v;
    v = xl.w + xr.w; v = v > 0.f ? v : NEG * v; p += a4.w * v;
#pragma unroll
    for (int off = G / 2; off > 0; off >>= 1) p += __shfl_xor(p, off, 64);
    float ex = expf(p);
    den += ex;
    acc.x += ex * xl.x;
    acc.y += ex * xl.y;
    acc.z += ex * xl.z;
    acc.w += ex * xl.w;
  }
  float inv = 1.f / fmaxf(den, 1e-16f);
  const float4 b4 = *(const float4*)(bias + lane * 4);
  float4 o;
  o.x = fmaxf(acc.x * inv + b4.x, 0.f);
  o.y = fmaxf(acc.y * inv + b4.y, 0.f);
  o.z = fmaxf(acc.z * inv + b4.z, 0.f);
  o.w = fmaxf(acc.w * inv + b4.w, 0.f);
  *(float4*)(h + (size_t)d * C + lane * 4) = o;
}

// ---------------- pooling: sorted-batch run-accumulate, flush on change ----
// thread owns channel c = tid&31 and 128 consecutive nodes; global atomics
// only at batch boundaries (~2 per thread) instead of per element.
__global__ void k_pool(const float* __restrict__ h3, const int* __restrict__ batch,
                       float* __restrict__ pooled, float* __restrict__ cnt) {
  constexpr int NPB = 1024;           // nodes per block
  constexpr int NPT = NPB / 8;        // nodes per thread run (block=256 thr, 8 rows)
  int c = threadIdx.x & 31;
  int r = threadIdx.x >> 5;
  int base = blockIdx.x * NPB + r * NPT;
  if (base >= N_NODES) return;
  int end = base + NPT;
  if (end > N_NODES) end = N_NODES;
  int cur_b = batch[base];
  float acc = 0.f, count = 0.f;
  for (int n = base; n < end; ++n) {
    int b = batch[n];
    if (b != cur_b) {
      atomicAdd(pooled + cur_b * HC2C + c, acc);
      if (c == 0) atomicAdd(cnt + cur_b, count);
      cur_b = b;
      acc = 0.f;
      count = 0.f;
    }
    acc += h3[(size_t)n * HC2C + c];
    count += 1.f;
  }
  atomicAdd(pooled + cur_b * HC2C + c, acc);
  if (c == 0) atomicAdd(cnt + cur_b, count);
}

// ---------------- tail ----------------
__global__ void k_sx(const float* __restrict__ h3, const int* __restrict__ root,
                     const float* __restrict__ pooled, const float* __restrict__ cnt,
                     const float* __restrict__ linW, const float* __restrict__ linb,
                     float* __restrict__ sx) {
  int t = blockIdx.x * blockDim.x + threadIdx.x;
  if (t >= NB * HC2C) return;
  int b = t >> 5, j = t & 31;
  int r = root[b];
  float inv = 1.f / fmaxf(cnt[b], 1.0f);
  float a = linb[j];
  for (int c = 0; c < HC2C; ++c) a += h3[(size_t)r * HC2C + c] * linW[c * HC2C + j];
  for (int c = 0; c < HC2C; ++c) a += (pooled[b * HC2C + c] * inv) * linW[(HC2C + c) * HC2C + j];
  sx[t] = a > 0.f ? a : 0.f;
}

__global__ void k_info1(const float* __restrict__ X, const int* __restrict__ root,
                        const float* __restrict__ c1w, const float* __restrict__ c1b,
                        float* __restrict__ info) {
  constexpr int L = IN_F - 2;
  int t = blockIdx.x * blockDim.x + threadIdx.x;
  if (t >= NB * L) return;
  int b = t / L, i = t - (t / L) * L;
  const float* xr = X + (size_t)root[b] * IN_F;
  info[t] = c1w[0] * xr[i] + c1w[1] * xr[i + 1] + c1w[2] * xr[i + 2] + c1b[0];
}

__global__ void k_info2(const float* __restrict__ info, const float* __restrict__ c2W,
                        const float* __restrict__ c2b, float* __restrict__ t1) {
  constexpr int L = IN_F - 2;
  int t = blockIdx.x * blockDim.x + threadIdx.x;
  if (t >= HC1C * NB) return;
  int j = t >> 6, b = t & 63;
  float a = c2b[j];
  for (int i = 0; i < L; ++i) a += c2W[j * L + i] * info[b * L + i];
  t1[t] = a > 0.f ? a : 0.f;
}

__global__ void k_info3(const float* __restrict__ t1, const float* __restrict__ c3W,
                        const float* __restrict__ c3b, float* __restrict__ t2) {
  int t = blockIdx.x * blockDim.x + threadIdx.x;
  if (t >= NB * NB) return;
  int j = t >> 6, b = t & 63;
  float a = c3b[j];
  for (int i = 0; i < HC1C; ++i) a += c3W[j * HC1C + i] * t1[i * NB + b];
  t2[t] = a > 0.f ? a : 0.f;
}

__global__ void k_info4(const float* __restrict__ t2, float* __restrict__ tt) {
  int t = blockIdx.x * blockDim.x + threadIdx.x;
  if (t >= NB * HC2C) return;
  int b = t >> 5, c = t & 31;
  float v = 0.5f * (t2[(2 * c) * NB + b] + t2[(2 * c + 1) * NB + b]);
  tt[b * HC2C + c] = v > 0.f ? v : 0.f;
}

__global__ void k_final(const float* __restrict__ sx, const float* __restrict__ tt,
                        const float* __restrict__ aW1, const float* __restrict__ ab1,
                        const float* __restrict__ aW2, const float* __restrict__ mW1,
                        const float* __restrict__ mb1, const float* __restrict__ mW2,
                        const float* __restrict__ mb2, float* __restrict__ out) {
  int b = threadIdx.x;
  if (b >= NB) return;
  const float* e0 = sx + b * HC2C;
  const float* e1 = tt + b * HC2C;
  float w[2];
#pragma unroll
  for (int r = 0; r < 2; ++r) {
    const float* eb = (r == 0) ? e0 : e1;
    float acc = 0.f;
    for (int j = 0; j < 16; ++j) {
      float z = ab1[j];
      for (int c = 0; c < HC2C; ++c) z += eb[c] * aW1[c * 16 + j];
      acc += tanhf(z) * aW2[j];
    }
    w[r] = acc;
  }
  float mx = fmaxf(w[0], w[1]);
  float x0 = expf(w[0] - mx), x1 = expf(w[1] - mx);
  float inv = 1.f / (x0 + x1);
  float b0 = x0 * inv, b1 = x1 * inv;
  float t16[16];
  for (int j = 0; j < 16; ++j) {
    float z = mb1[j];
    for (int c = 0; c < HC2C; ++c) z += (b0 * e0[c] + b1 * e1[c]) * mW1[c * 16 + j];
    t16[j] = tanhf(z);
  }
  float l0 = mb2[0], l1 = mb2[1];
  for (int j = 0; j < 16; ++j) {
    l0 += t16[j] * mW2[j * 2 + 0];
    l1 += t16[j] * mW2[j * 2 + 1];
  }
  float m2 = fmaxf(l0, l1);
  float y0 = expf(l0 - m2), y1 = expf(l1 - m2);
  float is = 1.f / (y0 + y1);
  out[b * 2 + 0] = y0 * is;
  out[b * 2 + 1] = y1 * is;
}

// ---------------- launcher ----------------
extern "C" void kernel_launch(void* const* d_in, const int* in_sizes, int n_in, void* d_out,
                              int out_size, void* d_ws, size_t ws_size, hipStream_t stream) {
  if (ws_size < WS_FLOATS * sizeof(float)) return;

  const float* s_x   = (const float*)d_in[0];
  const int*   edge  = (const int*)d_in[1];
  const int*   batch = (const int*)d_in[2];
  const int*   root  = (const int*)d_in[3];
  const float* Wv    = (const float*)d_in[8];
  const float* bv    = (const float*)d_in[9];
  const float* Wl1   = (const float*)d_in[10];
  const float* bl1   = (const float*)d_in[11];
  const float* Wr1   = (const float*)d_in[12];
  const float* br1   = (const float*)d_in[13];
  const float* att1  = (const float*)d_in[14];
  const float* bias1 = (const float*)d_in[15];
  const float* Wl2   = (const float*)d_in[16];
  const float* bl2   = (const float*)d_in[17];
  const float* Wr2   = (const float*)d_in[18];
  const float* br2   = (const float*)d_in[19];
  const float* att2  = (const float*)d_in[20];
  const float* bias2 = (const float*)d_in[21];
  const float* Wl3   = (const float*)d_in[22];
  const float* bl3   = (const float*)d_in[23];
  const float* Wr3   = (const float*)d_in[24];
  const float* br3   = (const float*)d_in[25];
  const float* att3  = (const float*)d_in[26];
  const float* bias3 = (const float*)d_in[27];
  const float* c1w   = (const float*)d_in[28];
  const float* c1b   = (const float*)d_in[29];
  const float* c2W   = (const float*)d_in[30];
  const float* c2b   = (const float*)d_in[31];
  const float* c3W   = (const float*)d_in[32];
  const float* c3b   = (const float*)d_in[33];
  const float* linW  = (const float*)d_in[34];
  const float* linb  = (const float*)d_in[35];
  const float* aW1   = (const float*)d_in[36];
  const float* ab1   = (const float*)d_in[37];
  const float* aW2   = (const float*)d_in[38];
  const float* mW1   = (const float*)d_in[39];
  const float* mb1   = (const float*)d_in[40];
  const float* mW2   = (const float*)d_in[41];
  const float* mb2   = (const float*)d_in[42];

  const int* src = edge;
  const int* dst = edge + N_EDGES;

  float* ws      = (float*)d_ws;
  float* WcL     = ws + OFF_WCL;
  float* WcR     = ws + OFF_WCR;
  float* bcL     = ws + OFF_BCL;
  float* bcR     = ws + OFF_BCR;
  float* xlr     = ws + OFF_XLR;
  float* hbuf    = ws + OFF_H;
  int*   deg     = (int*)(ws + OFF_DEG);
  int*   row_ptr = (int*)(ws + OFF_ROWPTR);
  int*   cursor  = (int*)(ws + OFF_CURSOR);
  int*   blks    = (int*)(ws + OFF_BLKS);
  int*   blko    = (int*)(ws + OFF_BLKO);
  int*   csr_src = (int*)(ws + OFF_CSRSRC);
  float* pooled  = ws + OFF_POOLED;
  float* cnt     = ws + OFF_CNT;
  float* sx      = ws + OFF_SX;
  float* info    = ws + OFF_INFO;
  float* t1      = ws + OFF_T1;
  float* t2      = ws + OFF_T2;
  float* tt      = ws + OFF_TT;
  float* out     = (float*)d_out;

  // ---- CSR build (by dst) ----
  hipMemsetAsync(deg, 0, N_NODES * sizeof(int), stream);
  k_hist<<<(N_EDGES + 255) / 256, 256, 0, stream>>>(dst, deg);
  k_scan_local<<<SCAN_NBLK, 256, 0, stream>>>(deg, row_ptr, blks);
  k_scan_blk<<<1, 512, 0, stream>>>(blks, blko);
  k_scan_add<<<SCAN_NBLK, 256, 0, stream>>>(row_ptr, blko, cursor);
  k_fill<<<(N_EDGES + 255) / 256, 256, 0, stream>>>(src, dst, cursor, csr_src);

  // ---- fold Wv into layer-1 projections ----
  k_wcomb<<<(IN_F * HC1C + 255) / 256, 256, 0, stream>>>(Wv, Wl1, Wr1, WcL, WcR);
  k_bcomb<<<1, HC1C, 0, stream>>>(bv, Wl1, bl1, Wr1, br1, bcL, bcR);

  // ---- GAT layer 1 (C=128, K=256) ----
  k_gemm_lr<8, 256, 128><<<N_NODES / 8, 128, 0, stream>>>(s_x, WcL, bcL, WcR, bcR, xlr);
  k_gat<128><<<(N_NODES * 32 + 255) / 256, 256, 0, stream>>>(xlr, row_ptr, csr_src, att1,
                                                             bias1, hbuf);

  // ---- GAT layer 2 (C=64, K=128) ----
  k_gemm_lr<8, 128, 64><<<N_NODES / 8, 64, 0, stream>>>(hbuf, Wl2, bl2, Wr2, br2, xlr);
  k_gat<64><<<(N_NODES * 16 + 255) / 256, 256, 0, stream>>>(xlr, row_ptr, csr_src, att2,
                                                            bias2, hbuf);

  // ---- GAT layer 3 (C=32, K=64) ----
  k_gemm_lr<8, 64, 32><<<N_NODES / 8, 32, 0, stream>>>(hbuf, Wl3, bl3, Wr3, br3, xlr);
  k_gat<32><<<(N_NODES * 8 + 255) / 256, 256, 0, stream>>>(xlr, row_ptr, csr_src, att3,
                                                           bias3, hbuf);

  // ---- pooling + root concat + lin ----
  hipMemsetAsync(pooled, 0, (NB * HC2C + NB) * sizeof(float), stream);
  k_pool<<<(N_NODES + 1023) / 1024, 256, 0, stream>>>(hbuf, batch, pooled, cnt);
  k_sx<<<(NB * HC2C + 255) / 256, 256, 0, stream>>>(hbuf, root, pooled, cnt, linW, linb, sx);

  // ---- info path ----
  k_info1<<<(NB * (IN_F - 2) + 255) / 256, 256, 0, stream>>>(s_x, root, c1w, c1b, info);
  k_info2<<<(HC1C * NB + 255) / 256, 256, 0, stream>>>(info, c2W, c2b, t1);
  k_info3<<<(NB * NB + 255) / 256, 256, 0, stream>>>(t1, c3W, c3b, t2);
  k_info4<<<(NB * HC2C + 255) / 256, 256, 0, stream>>>(t2, tt);

  // ---- attention combine + classifier ----
  k_final<<<1, NB, 0, stream>>>(sx, tt, aW1, ab1, aW2, mW1, mb1, mW2, mb2, out);
}

// Round 4
// 723.784 us; speedup vs baseline: 8.9272x; 1.2109x over previous
//
#include <hip/hip_runtime.h>
#include <hip/hip_bf16.h>
#include <math.h>

typedef unsigned short ushort_t;
typedef __attribute__((ext_vector_type(8))) short bfrag;   // 8 bf16 = 4 VGPRs
typedef __attribute__((ext_vector_type(4))) float ffrag;   // 4 fp32 acc

// ---------------- problem constants ----------------
constexpr int N_NODES = 100000;
constexpr int N_EDGES = 800000;
constexpr int NB      = 64;
constexpr int IN_F    = 256;
constexpr int HC1C    = 128;
constexpr int HC2C    = 32;
constexpr int SA_D    = 350;
constexpr float NEG   = 0.2f;

constexpr int SCAN_NBLK = (N_NODES + 255) / 256;  // 391
constexpr int MTILES    = (N_NODES + 63) / 64;    // 1563

// ---------------- workspace layout (float-sized slots) ----------------
// WT buffers are ushort regions (hi block then lo block), sized in float slots.
constexpr size_t OFF_WT1    = 0;                                   // 2*(256*256) ush = 65536 f
constexpr size_t OFF_WT2    = OFF_WT1 + 65536;                     // 2*(128*128) ush = 16384 f
constexpr size_t OFF_WT3    = OFF_WT2 + 16384;                     // 2*(64*64) ush = 4096 f
constexpr size_t OFF_BC1    = OFF_WT3 + 4096;                      // 256
constexpr size_t OFF_BC2    = OFF_BC1 + 256;                       // 128
constexpr size_t OFF_BC3    = OFF_BC2 + 128;                       // 64
constexpr size_t OFF_XLR    = OFF_BC3 + 64;                        // N*256
constexpr size_t OFF_H      = OFF_XLR + (size_t)N_NODES * 256;     // N*128
constexpr size_t OFF_DEG    = OFF_H + (size_t)N_NODES * 128;       // N ints
constexpr size_t OFF_ROWPTR = OFF_DEG + N_NODES;                   // N+1 ints
constexpr size_t OFF_CURSOR = OFF_ROWPTR + N_NODES + 1;            // N ints
constexpr size_t OFF_BLKS   = OFF_CURSOR + N_NODES;                // 512 ints
constexpr size_t OFF_BLKO   = OFF_BLKS + 512;                      // 512 ints
constexpr size_t OFF_CSRSRC = OFF_BLKO + 512;                      // E ints
constexpr size_t OFF_POOLED = OFF_CSRSRC + N_EDGES;                // 64*32
constexpr size_t OFF_CNT    = OFF_POOLED + NB * HC2C;              // 64
constexpr size_t OFF_SX     = OFF_CNT + NB;                        // 64*32
constexpr size_t OFF_INFO   = OFF_SX + NB * HC2C;                  // 64*254
constexpr size_t OFF_T1     = OFF_INFO + (size_t)NB * (IN_F - 2);  // 128*64
constexpr size_t OFF_T2     = OFF_T1 + (size_t)HC1C * NB;          // 64*64
constexpr size_t OFF_TT     = OFF_T2 + (size_t)NB * NB;            // 64*32
constexpr size_t WS_FLOATS  = OFF_TT + NB * HC2C;

// ---------------- bf16 split helpers ----------------
__device__ __forceinline__ ushort_t f2bf(float f) {
  union { float f; unsigned int u; } a;
  a.f = f;
  unsigned int r = a.u + 0x7FFFu + ((a.u >> 16) & 1u);
  return (ushort_t)(r >> 16);
}
__device__ __forceinline__ float bf2f(ushort_t h) {
  union { unsigned int u; float f; } a;
  a.u = ((unsigned int)h) << 16;
  return a.f;
}

// ---------------- weight fold / pack (transposed, split hi/lo) ----------------
// Layer 1: WT1[n][k] = (Wv @ W{l,r}1)[k][n'] split into hi (offset 0) / lo (offset 65536)
__global__ void k_wcomb(const float* __restrict__ Wv, const float* __restrict__ Wl1,
                        const float* __restrict__ Wr1, ushort_t* __restrict__ WT) {
  int t = blockIdx.x * blockDim.x + threadIdx.x;
  if (t >= 256 * 256) return;
  int n = t & 255;   // output column (0..255: L then R)
  int k = t >> 8;    // input-feature index (0..255)
  const float* Wx = (n < 128) ? Wl1 : Wr1;
  int j = n & 127;
  float a = 0.f;
  for (int kk = 0; kk < SA_D; ++kk) a += Wv[k * SA_D + kk] * Wx[kk * 128 + j];
  ushort_t h = f2bf(a);
  WT[(size_t)n * 256 + k] = h;
  WT[65536 + (size_t)n * 256 + k] = f2bf(a - bf2f(h));
}

__global__ void k_bcomb(const float* __restrict__ bv, const float* __restrict__ Wl1,
                        const float* __restrict__ bl1, const float* __restrict__ Wr1,
                        const float* __restrict__ br1, float* __restrict__ bc) {
  int n = threadIdx.x;
  if (n >= 256) return;
  const float* Wx = (n < 128) ? Wl1 : Wr1;
  const float* bx = (n < 128) ? bl1 : br1;
  int j = n & 127;
  float a = bx[j];
  for (int kk = 0; kk < SA_D; ++kk) a += bv[kk] * Wx[kk * 128 + j];
  bc[n] = a;
}

// Layers 2/3: WT[n][k] from row-major Wl/Wr (K x C), split hi/lo; bias pack.
template <int K, int C>
__global__ void k_wpack(const float* __restrict__ Wl, const float* __restrict__ bl,
                        const float* __restrict__ Wr, const float* __restrict__ br,
                        ushort_t* __restrict__ WT, float* __restrict__ bc) {
  constexpr int NN = 2 * C;
  int t = blockIdx.x * blockDim.x + threadIdx.x;
  if (t < NN) bc[t] = (t < C) ? bl[t] : br[t - C];
  if (t >= NN * K) return;
  int n = t % NN;
  int k = t / NN;
  float v = (n < C) ? Wl[k * C + n] : Wr[k * C + (n - C)];
  ushort_t h = f2bf(v);
  WT[(size_t)n * K + k] = h;
  WT[(size_t)NN * K + (size_t)n * K + k] = f2bf(v - bf2f(h));
}

// ---------------- CSR build ----------------
__global__ void k_hist(const int* __restrict__ dst, int* __restrict__ deg) {
  int e = blockIdx.x * blockDim.x + threadIdx.x;
  if (e < N_EDGES) atomicAdd(deg + dst[e], 1);
}

__global__ void k_scan_local(const int* __restrict__ deg, int* __restrict__ row_ptr,
                             int* __restrict__ blk_sum) {
  __shared__ int sh[256];
  int t = threadIdx.x;
  int i = blockIdx.x * 256 + t;
  int v = (i < N_NODES) ? deg[i] : 0;
  sh[t] = v;
  __syncthreads();
  for (int off = 1; off < 256; off <<= 1) {
    int add = (t >= off) ? sh[t - off] : 0;
    __syncthreads();
    sh[t] += add;
    __syncthreads();
  }
  if (i < N_NODES) row_ptr[i] = sh[t] - v;
  if (t == 255) blk_sum[blockIdx.x] = sh[255];
}

__global__ void k_scan_blk(const int* __restrict__ blk_sum, int* __restrict__ blk_off) {
  __shared__ int sh[512];
  int t = threadIdx.x;
  int v = (t < SCAN_NBLK) ? blk_sum[t] : 0;
  sh[t] = v;
  __syncthreads();
  for (int off = 1; off < 512; off <<= 1) {
    int add = (t >= off) ? sh[t - off] : 0;
    __syncthreads();
    sh[t] += add;
    __syncthreads();
  }
  blk_off[t] = sh[t] - v;
}

__global__ void k_scan_add(int* __restrict__ row_ptr, const int* __restrict__ blk_off,
                           int* __restrict__ cursor) {
  int i = blockIdx.x * blockDim.x + threadIdx.x;
  if (i < N_NODES) {
    int v = row_ptr[i] + blk_off[i >> 8];
    row_ptr[i] = v;
    cursor[i] = v;
  }
  if (i == 0) row_ptr[N_NODES] = N_EDGES;
}

__global__ void k_fill(const int* __restrict__ src, const int* __restrict__ dst,
                       int* __restrict__ cursor, int* __restrict__ csr_src) {
  int e = blockIdx.x * blockDim.x + threadIdx.x;
  if (e >= N_EDGES) return;
  int pos = atomicAdd(cursor + dst[e], 1);
  csr_src[pos] = src[e];
}

// ---------------- split-bf16 MFMA GEMM: out[m][NN] = x[m][K] @ W + bc ----------------
// WT: ushort [NN][K] hi block, then lo block (offset NN*K). BM=64 (4 waves x 16 rows),
// BN cols per block, BK=32 per step. Fragments: A/B row = lane&15, k = quad*8+j;
// C/D col = lane&15, row = quad*4+reg  [verified layouts, m89/m120].
template <int K, int NN, int BN>
__global__ __launch_bounds__(256) void k_gemm_mfma(const float* __restrict__ x,
                                                   const ushort_t* __restrict__ WT,
                                                   const float* __restrict__ bc,
                                                   float* __restrict__ out, int M) {
  constexpr int BM  = 64;
  constexpr int BK  = 32;
  constexpr int LDA = BK + 8;    // padded stride (ushorts): 80B rows -> 2-way max conflicts
  constexpr int NCT = BN / 16;   // col tiles per wave
  __shared__ ushort_t As[2][BM * LDA];
  __shared__ ushort_t Bs[2][BN * LDA];
  const int tid  = threadIdx.x;
  const int wave = tid >> 6;
  const int lane = tid & 63;
  const int quad = lane >> 4;
  const int l16  = lane & 15;
  const int m0   = blockIdx.x * BM;
  const int n0   = blockIdx.y * BN;

  ffrag acc[NCT];
#pragma unroll
  for (int i = 0; i < NCT; ++i) acc[i] = ffrag{0.f, 0.f, 0.f, 0.f};

  for (int k0 = 0; k0 < K; k0 += BK) {
    __syncthreads();
    // stage A: BM x BK fp32 -> hi/lo bf16 (one 32B read per thread)
    {
      int row = tid >> 2;
      int ks  = (tid & 3) * 8;
      int gm  = m0 + row;
      if (gm >= M) gm = M - 1;
      const float* srcp = x + (size_t)gm * K + k0 + ks;
      float4 v0 = ((const float4*)srcp)[0];
      float4 v1 = ((const float4*)srcp)[1];
      float v[8] = {v0.x, v0.y, v0.z, v0.w, v1.x, v1.y, v1.z, v1.w};
      ushort_t hi[8], lo[8];
#pragma unroll
      for (int j = 0; j < 8; ++j) {
        hi[j] = f2bf(v[j]);
        lo[j] = f2bf(v[j] - bf2f(hi[j]));
      }
      *(bfrag*)&As[0][row * LDA + ks] = *(const bfrag*)hi;
      *(bfrag*)&As[1][row * LDA + ks] = *(const bfrag*)lo;
    }
    // stage B: BN x BK hi/lo bf16 (16B copies)
    for (int i = tid; i < BN * 4; i += 256) {
      int n  = i >> 2;
      int ks = (i & 3) * 8;
      const ushort_t* gh = WT + (size_t)(n0 + n) * K + k0 + ks;
      *(bfrag*)&Bs[0][n * LDA + ks] = *(const bfrag*)gh;
      *(bfrag*)&Bs[1][n * LDA + ks] = *(const bfrag*)(gh + (size_t)NN * K);
    }
    __syncthreads();

    bfrag a_hi = *(const bfrag*)&As[0][(wave * 16 + l16) * LDA + quad * 8];
    bfrag a_lo = *(const bfrag*)&As[1][(wave * 16 + l16) * LDA + quad * 8];
#pragma unroll
    for (int ct = 0; ct < NCT; ++ct) {
      bfrag b_hi = *(const bfrag*)&Bs[0][(ct * 16 + l16) * LDA + quad * 8];
      bfrag b_lo = *(const bfrag*)&Bs[1][(ct * 16 + l16) * LDA + quad * 8];
      acc[ct] = __builtin_amdgcn_mfma_f32_16x16x32_bf16(a_hi, b_hi, acc[ct], 0, 0, 0);
      acc[ct] = __builtin_amdgcn_mfma_f32_16x16x32_bf16(a_hi, b_lo, acc[ct], 0, 0, 0);
      acc[ct] = __builtin_amdgcn_mfma_f32_16x16x32_bf16(a_lo, b_hi, acc[ct], 0, 0, 0);
    }
  }

#pragma unroll
  for (int ct = 0; ct < NCT; ++ct) {
    int n = n0 + ct * 16 + l16;
    float b = bc[n];
#pragma unroll
    for (int r = 0; r < 4; ++r) {
      int m = m0 + wave * 16 + quad * 4 + r;
      if (m < M) out[(size_t)m * NN + n] = acc[ct][r] + b;
    }
  }
}

// ---------------- fused per-node GAT edge pass ----------------
template <int C>
__global__ void k_gat(const float* __restrict__ xlr, const int* __restrict__ row_ptr,
                      const int* __restrict__ csr_src, const float* __restrict__ att,
                      const float* __restrict__ bias, float* __restrict__ h) {
  constexpr int G = C / 4;
  constexpr int RS = 2 * C;
  int t = blockIdx.x * blockDim.x + threadIdx.x;
  int d = t / G;
  int lane = t - d * G;
  if (d >= N_NODES) return;
  const float4 xr = *(const float4*)(xlr + (size_t)d * RS + C + lane * 4);
  const float4 a4 = *(const float4*)(att + lane * 4);
  float4 acc = {0.f, 0.f, 0.f, 0.f};
  float den = 0.f;
  const int e0 = row_ptr[d], e1 = row_ptr[d + 1];
  for (int i = e0; i < e1; ++i) {
    int s = csr_src[i];
    float4 xl = *(const float4*)(xlr + (size_t)s * RS + lane * 4);
    float v, p = 0.f;
    v = xl.x + xr.x; v = v > 0.f ? v : NEG * v; p += a4.x * v;
    v = xl.y + xr.y; v = v > 0.f ? v : NEG * v; p += a4.y * v;
    v = xl.z + xr.z; v = v > 0.f ? v : NEG * v; p += a4.z * v;
    v = xl.w + xr.w; v = v > 0.f ? v : NEG * v; p += a4.w * v;
#pragma unroll
    for (int off = G / 2; off > 0; off >>= 1) p += __shfl_xor(p, off, 64);
    float ex = expf(p);
    den += ex;
    acc.x += ex * xl.x;
    acc.y += ex * xl.y;
    acc.z += ex * xl.z;
    acc.w += ex * xl.w;
  }
  float inv = 1.f / fmaxf(den, 1e-16f);
  const float4 b4 = *(const float4*)(bias + lane * 4);
  float4 o;
  o.x = fmaxf(acc.x * inv + b4.x, 0.f);
  o.y = fmaxf(acc.y * inv + b4.y, 0.f);
  o.z = fmaxf(acc.z * inv + b4.z, 0.f);
  o.w = fmaxf(acc.w * inv + b4.w, 0.f);
  *(float4*)(h + (size_t)d * C + lane * 4) = o;
}

// ---------------- pooling: sorted-batch run-accumulate ----------------
__global__ void k_pool(const float* __restrict__ h3, const int* __restrict__ batch,
                       float* __restrict__ pooled, float* __restrict__ cnt) {
  constexpr int NPB = 1024;
  constexpr int NPT = NPB / 8;
  int c = threadIdx.x & 31;
  int r = threadIdx.x >> 5;
  int base = blockIdx.x * NPB + r * NPT;
  if (base >= N_NODES) return;
  int end = base + NPT;
  if (end > N_NODES) end = N_NODES;
  int cur_b = batch[base];
  float acc = 0.f, count = 0.f;
  for (int n = base; n < end; ++n) {
    int b = batch[n];
    if (b != cur_b) {
      atomicAdd(pooled + cur_b * HC2C + c, acc);
      if (c == 0) atomicAdd(cnt + cur_b, count);
      cur_b = b;
      acc = 0.f;
      count = 0.f;
    }
    acc += h3[(size_t)n * HC2C + c];
    count += 1.f;
  }
  atomicAdd(pooled + cur_b * HC2C + c, acc);
  if (c == 0) atomicAdd(cnt + cur_b, count);
}

// ---------------- tail ----------------
__global__ void k_sx(const float* __restrict__ h3, const int* __restrict__ root,
                     const float* __restrict__ pooled, const float* __restrict__ cnt,
                     const float* __restrict__ linW, const float* __restrict__ linb,
                     float* __restrict__ sx) {
  int t = blockIdx.x * blockDim.x + threadIdx.x;
  if (t >= NB * HC2C) return;
  int b = t >> 5, j = t & 31;
  int r = root[b];
  float inv = 1.f / fmaxf(cnt[b], 1.0f);
  float a = linb[j];
  for (int c = 0; c < HC2C; ++c) a += h3[(size_t)r * HC2C + c] * linW[c * HC2C + j];
  for (int c = 0; c < HC2C; ++c) a += (pooled[b * HC2C + c] * inv) * linW[(HC2C + c) * HC2C + j];
  sx[t] = a > 0.f ? a : 0.f;
}

__global__ void k_info1(const float* __restrict__ X, const int* __restrict__ root,
                        const float* __restrict__ c1w, const float* __restrict__ c1b,
                        float* __restrict__ info) {
  constexpr int L = IN_F - 2;
  int t = blockIdx.x * blockDim.x + threadIdx.x;
  if (t >= NB * L) return;
  int b = t / L, i = t - (t / L) * L;
  const float* xr = X + (size_t)root[b] * IN_F;
  info[t] = c1w[0] * xr[i] + c1w[1] * xr[i + 1] + c1w[2] * xr[i + 2] + c1b[0];
}

__global__ void k_info2(const float* __restrict__ info, const float* __restrict__ c2W,
                        const float* __restrict__ c2b, float* __restrict__ t1) {
  constexpr int L = IN_F - 2;
  int t = blockIdx.x * blockDim.x + threadIdx.x;
  if (t >= HC1C * NB) return;
  int j = t >> 6, b = t & 63;
  float a = c2b[j];
  for (int i = 0; i < L; ++i) a += c2W[j * L + i] * info[b * L + i];
  t1[t] = a > 0.f ? a : 0.f;
}

__global__ void k_info3(const float* __restrict__ t1, const float* __restrict__ c3W,
                        const float* __restrict__ c3b, float* __restrict__ t2) {
  int t = blockIdx.x * blockDim.x + threadIdx.x;
  if (t >= NB * NB) return;
  int j = t >> 6, b = t & 63;
  float a = c3b[j];
  for (int i = 0; i < HC1C; ++i) a += c3W[j * HC1C + i] * t1[i * NB + b];
  t2[t] = a > 0.f ? a : 0.f;
}

__global__ void k_info4(const float* __restrict__ t2, float* __restrict__ tt) {
  int t = blockIdx.x * blockDim.x + threadIdx.x;
  if (t >= NB * HC2C) return;
  int b = t >> 5, c = t & 31;
  float v = 0.5f * (t2[(2 * c) * NB + b] + t2[(2 * c + 1) * NB + b]);
  tt[b * HC2C + c] = v > 0.f ? v : 0.f;
}

__global__ void k_final(const float* __restrict__ sx, const float* __restrict__ tt,
                        const float* __restrict__ aW1, const float* __restrict__ ab1,
                        const float* __restrict__ aW2, const float* __restrict__ mW1,
                        const float* __restrict__ mb1, const float* __restrict__ mW2,
                        const float* __restrict__ mb2, float* __restrict__ out) {
  int b = threadIdx.x;
  if (b >= NB) return;
  const float* e0 = sx + b * HC2C;
  const float* e1 = tt + b * HC2C;
  float w[2];
#pragma unroll
  for (int r = 0; r < 2; ++r) {
    const float* eb = (r == 0) ? e0 : e1;
    float acc = 0.f;
    for (int j = 0; j < 16; ++j) {
      float z = ab1[j];
      for (int c = 0; c < HC2C; ++c) z += eb[c] * aW1[c * 16 + j];
      acc += tanhf(z) * aW2[j];
    }
    w[r] = acc;
  }
  float mx = fmaxf(w[0], w[1]);
  float x0 = expf(w[0] - mx), x1 = expf(w[1] - mx);
  float inv = 1.f / (x0 + x1);
  float b0 = x0 * inv, b1 = x1 * inv;
  float t16[16];
  for (int j = 0; j < 16; ++j) {
    float z = mb1[j];
    for (int c = 0; c < HC2C; ++c) z += (b0 * e0[c] + b1 * e1[c]) * mW1[c * 16 + j];
    t16[j] = tanhf(z);
  }
  float l0 = mb2[0], l1 = mb2[1];
  for (int j = 0; j < 16; ++j) {
    l0 += t16[j] * mW2[j * 2 + 0];
    l1 += t16[j] * mW2[j * 2 + 1];
  }
  float m2 = fmaxf(l0, l1);
  float y0 = expf(l0 - m2), y1 = expf(l1 - m2);
  float is = 1.f / (y0 + y1);
  out[b * 2 + 0] = y0 * is;
  out[b * 2 + 1] = y1 * is;
}

// ---------------- launcher ----------------
extern "C" void kernel_launch(void* const* d_in, const int* in_sizes, int n_in, void* d_out,
                              int out_size, void* d_ws, size_t ws_size, hipStream_t stream) {
  if (ws_size < WS_FLOATS * sizeof(float)) return;

  const float* s_x   = (const float*)d_in[0];
  const int*   edge  = (const int*)d_in[1];
  const int*   batch = (const int*)d_in[2];
  const int*   root  = (const int*)d_in[3];
  const float* Wv    = (const float*)d_in[8];
  const float* bv    = (const float*)d_in[9];
  const float* Wl1   = (const float*)d_in[10];
  const float* bl1   = (const float*)d_in[11];
  const float* Wr1   = (const float*)d_in[12];
  const float* br1   = (const float*)d_in[13];
  const float* att1  = (const float*)d_in[14];
  const float* bias1 = (const float*)d_in[15];
  const float* Wl2   = (const float*)d_in[16];
  const float* bl2   = (const float*)d_in[17];
  const float* Wr2   = (const float*)d_in[18];
  const float* br2   = (const float*)d_in[19];
  const float* att2  = (const float*)d_in[20];
  const float* bias2 = (const float*)d_in[21];
  const float* Wl3   = (const float*)d_in[22];
  const float* bl3   = (const float*)d_in[23];
  const float* Wr3   = (const float*)d_in[24];
  const float* br3   = (const float*)d_in[25];
  const float* att3  = (const float*)d_in[26];
  const float* bias3 = (const float*)d_in[27];
  const float* c1w   = (const float*)d_in[28];
  const float* c1b   = (const float*)d_in[29];
  const float* c2W   = (const float*)d_in[30];
  const float* c2b   = (const float*)d_in[31];
  const float* c3W   = (const float*)d_in[32];
  const float* c3b   = (const float*)d_in[33];
  const float* linW  = (const float*)d_in[34];
  const float* linb  = (const float*)d_in[35];
  const float* aW1   = (const float*)d_in[36];
  const float* ab1   = (const float*)d_in[37];
  const float* aW2   = (const float*)d_in[38];
  const float* mW1   = (const float*)d_in[39];
  const float* mb1   = (const float*)d_in[40];
  const float* mW2   = (const float*)d_in[41];
  const float* mb2   = (const float*)d_in[42];

  const int* src = edge;
  const int* dst = edge + N_EDGES;

  float*    ws      = (float*)d_ws;
  ushort_t* WT1     = (ushort_t*)(ws + OFF_WT1);
  ushort_t* WT2     = (ushort_t*)(ws + OFF_WT2);
  ushort_t* WT3     = (ushort_t*)(ws + OFF_WT3);
  float*    bc1     = ws + OFF_BC1;
  float*    bc2     = ws + OFF_BC2;
  float*    bc3     = ws + OFF_BC3;
  float*    xlr     = ws + OFF_XLR;
  float*    hbuf    = ws + OFF_H;
  int*      deg     = (int*)(ws + OFF_DEG);
  int*      row_ptr = (int*)(ws + OFF_ROWPTR);
  int*      cursor  = (int*)(ws + OFF_CURSOR);
  int*      blks    = (int*)(ws + OFF_BLKS);
  int*      blko    = (int*)(ws + OFF_BLKO);
  int*      csr_src = (int*)(ws + OFF_CSRSRC);
  float*    pooled  = ws + OFF_POOLED;
  float*    cnt     = ws + OFF_CNT;
  float*    sx      = ws + OFF_SX;
  float*    info    = ws + OFF_INFO;
  float*    t1      = ws + OFF_T1;
  float*    t2      = ws + OFF_T2;
  float*    tt      = ws + OFF_TT;
  float*    out     = (float*)d_out;

  // ---- CSR build (by dst) ----
  hipMemsetAsync(deg, 0, N_NODES * sizeof(int), stream);
  k_hist<<<(N_EDGES + 255) / 256, 256, 0, stream>>>(dst, deg);
  k_scan_local<<<SCAN_NBLK, 256, 0, stream>>>(deg, row_ptr, blks);
  k_scan_blk<<<1, 512, 0, stream>>>(blks, blko);
  k_scan_add<<<SCAN_NBLK, 256, 0, stream>>>(row_ptr, blko, cursor);
  k_fill<<<(N_EDGES + 255) / 256, 256, 0, stream>>>(src, dst, cursor, csr_src);

  // ---- weight fold / pack (transposed, hi/lo split) ----
  k_wcomb<<<(256 * 256) / 256, 256, 0, stream>>>(Wv, Wl1, Wr1, WT1);
  k_bcomb<<<1, 256, 0, stream>>>(bv, Wl1, bl1, Wr1, br1, bc1);
  k_wpack<128, 64><<<(128 * 128 + 255) / 256, 256, 0, stream>>>(Wl2, bl2, Wr2, br2, WT2, bc2);
  k_wpack<64, 32><<<(64 * 64 + 255) / 256, 256, 0, stream>>>(Wl3, bl3, Wr3, br3, WT3, bc3);

  // ---- GAT layer 1 (K=256, N=256) ----
  k_gemm_mfma<256, 256, 128><<<dim3(MTILES, 2), 256, 0, stream>>>(s_x, WT1, bc1, xlr, N_NODES);
  k_gat<128><<<(N_NODES * 32 + 255) / 256, 256, 0, stream>>>(xlr, row_ptr, csr_src, att1,
                                                             bias1, hbuf);

  // ---- GAT layer 2 (K=128, N=128) ----
  k_gemm_mfma<128, 128, 128><<<dim3(MTILES, 1), 256, 0, stream>>>(hbuf, WT2, bc2, xlr, N_NODES);
  k_gat<64><<<(N_NODES * 16 + 255) / 256, 256, 0, stream>>>(xlr, row_ptr, csr_src, att2,
                                                            bias2, hbuf);

  // ---- GAT layer 3 (K=64, N=64) ----
  k_gemm_mfma<64, 64, 64><<<dim3(MTILES, 1), 256, 0, stream>>>(hbuf, WT3, bc3, xlr, N_NODES);
  k_gat<32><<<(N_NODES * 8 + 255) / 256, 256, 0, stream>>>(xlr, row_ptr, csr_src, att3,
                                                           bias3, hbuf);

  // ---- pooling + root concat + lin ----
  hipMemsetAsync(pooled, 0, (NB * HC2C + NB) * sizeof(float), stream);
  k_pool<<<(N_NODES + 1023) / 1024, 256, 0, stream>>>(hbuf, batch, pooled, cnt);
  k_sx<<<(NB * HC2C + 255) / 256, 256, 0, stream>>>(hbuf, root, pooled, cnt, linW, linb, sx);

  // ---- info path ----
  k_info1<<<(NB * (IN_F - 2) + 255) / 256, 256, 0, stream>>>(s_x, root, c1w, c1b, info);
  k_info2<<<(HC1C * NB + 255) / 256, 256, 0, stream>>>(info, c2W, c2b, t1);
  k_info3<<<(NB * NB + 255) / 256, 256, 0, stream>>>(t1, c3W, c3b, t2);
  k_info4<<<(NB * HC2C + 255) / 256, 256, 0, stream>>>(t2, tt);

  // ---- attention combine + classifier ----
  k_final<<<1, NB, 0, stream>>>(sx, tt, aW1, ab1, aW2, mW1, mb1, mW2, mb2, out);
}